// Round 9
// baseline (529.596 us; speedup 1.0000x reference)
//
#include <hip/hip_runtime.h>
#include <stdint.h>

// Problem constants (from reference)
#define NN      5000
#define NE      4000
#define NB      8
#define TSTEPS  256
#define NDELAY  15
#define NW      157          // uint32 words covering 5000 presyn bits
#define NIPAD   5120         // padded neuron dim (columns of maskT2)
#define RW      160          // ring/mask row stride in words
#define IPB     512          // 256 neurons x 2 K-halves
#define NSL     20           // 256-neuron slices
#define NBLK    (NB*NSL)     // 160 blocks -> 1 per CU (LDS-forced), 2 waves/SIMD
#define RING_SLOTS 32
#define CH      4            // chunk length (64 chunks)
#define BARSTRIDE 16         // ints between chunk counters (64B apart)

// Workspace layout (bytes)
#define MASK_BYTES (RW*NIPAD*4)          // 3,276,800
#define BAR_OFF    MASK_BYTES
#define BAR_BYTES  (64*BARSTRIDE*4)      // 4,096 (64 chunk counters)
#define RING_OFF   (BAR_OFF + BAR_BYTES)
#define RING_BYTES (RING_SLOTS*NB*RW*4)  // 163,840
#define ZERO_BYTES (RING_OFF + RING_BYTES)

// ---------------------------------------------------------------------------
// Kernel 1: bit-pack connectivity, word-major-transposed:
//   maskT2[w*NIPAD + i] bit (j&31), w=j>>5, set iff W[i,j] != 0.
// ---------------------------------------------------------------------------
__global__ void _Brunel_build_mask(const float* __restrict__ W,
                                   uint32_t* __restrict__ maskT2)
{
    int j = blockIdx.x * blockDim.x + threadIdx.x;   // presyn 0..5119
    int i = blockIdx.y;                              // postsyn row 0..4999
    int lane = threadIdx.x & 63;
    bool nz = false;
    if (j < NN) nz = (W[(size_t)i * NN + j] != 0.0f);
    unsigned long long m = __ballot(nz);
    if ((lane & 31) == 0 && j < NN) {
        uint32_t wd = (lane == 0) ? (uint32_t)m : (uint32_t)(m >> 32);
        maskT2[(size_t)(j >> 5) * NIPAD + i] = wd;
    }
}

// extract bits at even positions of a 64-bit mask -> 32-bit word
__device__ __forceinline__ uint32_t compress_even(unsigned long long bm)
{
    bm &= 0x5555555555555555ull;
    bm = (bm | (bm >> 1))  & 0x3333333333333333ull;
    bm = (bm | (bm >> 2))  & 0x0F0F0F0F0F0F0F0Full;
    bm = (bm | (bm >> 4))  & 0x00FF00FF00FF00FFull;
    bm = (bm | (bm >> 8))  & 0x0000FFFF0000FFFFull;
    bm = (bm | (bm >> 16));
    return (uint32_t)bm;
}

// ---------------------------------------------------------------------------
// Kernel 2: persistent SNN sim, K-split x2.
//  Lane pair (nl, q): q=0 owns words 0..79, q=1 owns words 80..156 of
//  neuron nl's mask row. Uniform passes: S = popc over own words (all),
//  V = popc over own slice of inh words 125..156. cE = S-V, cI = V after
//  one __shfl_xor(.,1) combine. 512-thr blocks, 163KB LDS -> 1 block/CU,
//  8 waves -> 2 waves/SIMD (latency hiding round 8 lacked).
//  Sync: round-8 coherence-point scheme (sc0sc1 ring/barc, per-chunk
//  counters, vmcnt(0)+syncthreads arrive), unchanged.
// ---------------------------------------------------------------------------
__global__ void __launch_bounds__(IPB, 2) _Brunel_persist(
    const float* __restrict__ ext,
    const uint32_t* __restrict__ maskT2,
    uint32_t* __restrict__ ring,
    int* __restrict__ barc,
    float* __restrict__ out_spk,
    float* __restrict__ out_vs)
{
    const int tx   = threadIdx.x;
    const int wv   = tx >> 6;          // wave 0..7 (32 neurons each)
    const int lane = tx & 63;
    const int nl   = tx >> 1;          // neuron-local 0..255
    const int q    = tx & 1;           // K-half
    const int bb   = blockIdx.x;
    const int b    = bb / NSL;
    const int sl   = bb % NSL;
    const int i    = sl * 256 + nl;
    const bool act = (i < NN);

    __shared__ __align__(16) uint32_t s_mask[256][156];   // 159,744 B
    __shared__ uint32_t s_mask156[256];                   //   1,024 B
    __shared__ __align__(16) uint32_t s_spk[CH][RW];      //   2,560 B
                                                          // = 163,328 B

    // ---- one-time: mask rows -> LDS (2 words per thread-iteration) ----
    for (int c = 0; c < 79; ++c) {
        int w = 2 * c + q;
        if (w < NW) {
            uint32_t mv = maskT2[(size_t)w * NIPAD + i];  // pad cols are 0
            if (w < 156) s_mask[nl][w] = mv;
            else         s_mask156[nl] = mv;
        }
    }
    for (int idx = tx; idx < CH * RW; idx += IPB)
        ((uint32_t*)s_spk)[idx] = 0u;
    __syncthreads();

    float v = 0.0f;
    const int wbase = 80 * q;          // own main-range base word

    for (int t0 = 0, m = 0; t0 < TSTEPS; t0 += CH, ++m) {
        // ---- prefetch external inputs ----
        float x0 = 0.f, x1 = 0.f, x2 = 0.f, x3 = 0.f;
        if (act) {
            const float* e0 = ext + ((size_t)t0 * NB + b) * NN + i;
            const size_t st = (size_t)NB * NN;
            x0 = e0[0]; x1 = e0[st]; x2 = e0[2 * st]; x3 = e0[3 * st];
        }

        // ---- wait for chunk m-3, then stage 4 delayed spike slots ----
        if (m >= 3) {
            if (tx == 0) {
                const int* c3 = barc + (size_t)(m - 3) * BARSTRIDE;
                while (__hip_atomic_load(c3, __ATOMIC_RELAXED,
                                         __HIP_MEMORY_SCOPE_AGENT) < NBLK)
                    __builtin_amdgcn_s_sleep(2);
            }
            __syncthreads();
            const int ts0 = t0 - NDELAY;
            for (int it = 0; it < 2; ++it) {
                int idx = tx + it * IPB;
                if (idx < CH * RW) {
                    int k = idx / RW, w = idx - k * RW;
                    int ts = ts0 + k;
                    ((uint32_t*)s_spk)[idx] = __hip_atomic_load(
                        &ring[((size_t)(ts & (RING_SLOTS - 1)) * NB + b) * RW + w],
                        __ATOMIC_RELAXED, __HIP_MEMORY_SCOPE_AGENT);
                }
            }
            __syncthreads();
        }

        // ---- main pass: S_k = popc over own words (uniform) ----
        int S0 = 0, S1 = 0, S2 = 0, S3 = 0;
        int V0 = 0, V1 = 0, V2 = 0, V3 = 0;
        const uint32_t* __restrict__ mrow = s_mask[nl];
#pragma unroll 4
        for (int c = 0; c < 20; ++c) {
            int w0 = wbase + 4 * c;
            if (w0 < 156) {                    // q=1,c=19 masked out
                uint4 m4 = *(const uint4*)(mrow + w0);
                uint4 a0 = *(const uint4*)(&s_spk[0][w0]);
                uint4 a1 = *(const uint4*)(&s_spk[1][w0]);
                uint4 a2 = *(const uint4*)(&s_spk[2][w0]);
                uint4 a3 = *(const uint4*)(&s_spk[3][w0]);
                S0 += __popc(m4.x & a0.x) + __popc(m4.y & a0.y)
                    + __popc(m4.z & a0.z) + __popc(m4.w & a0.w);
                S1 += __popc(m4.x & a1.x) + __popc(m4.y & a1.y)
                    + __popc(m4.z & a1.z) + __popc(m4.w & a1.w);
                S2 += __popc(m4.x & a2.x) + __popc(m4.y & a2.y)
                    + __popc(m4.z & a2.z) + __popc(m4.w & a2.w);
                S3 += __popc(m4.x & a3.x) + __popc(m4.y & a3.y)
                    + __popc(m4.z & a3.z) + __popc(m4.w & a3.w);
            }
        }
        // ---- inh pass: V_k over words 125+16q .. (uniform, b32) ----
#pragma unroll 4
        for (int ww = 0; ww < 16; ++ww) {
            int w = 125 + 16 * q + ww;
            if (w < 156) {                     // q=1,ww=15 (word156) excluded
                uint32_t mw = mrow[w];
                V0 += __popc(mw & s_spk[0][w]);
                V1 += __popc(mw & s_spk[1][w]);
                V2 += __popc(mw & s_spk[2][w]);
                V3 += __popc(mw & s_spk[3][w]);
            }
        }
        {   // word 156 (inh): counted exactly once (added on q==0 lanes)
            uint32_t m156 = s_mask156[nl];
            int p0 = __popc(m156 & s_spk[0][156]);
            int p1 = __popc(m156 & s_spk[1][156]);
            int p2 = __popc(m156 & s_spk[2][156]);
            int p3 = __popc(m156 & s_spk[3][156]);
            if (q == 0) {
                S0 += p0; S1 += p1; S2 += p2; S3 += p3;
                V0 += p0; V1 += p1; V2 += p2; V3 += p3;
            }
        }
        // ---- combine K-halves (partner lane): totals in both lanes ----
        S0 += __shfl_xor(S0, 1); S1 += __shfl_xor(S1, 1);
        S2 += __shfl_xor(S2, 1); S3 += __shfl_xor(S3, 1);
        V0 += __shfl_xor(V0, 1); V1 += __shfl_xor(V1, 1);
        V2 += __shfl_xor(V2, 1); V3 += __shfl_xor(V3, 1);

        // ---- 4 sequential neuron updates (both lanes redundantly) ----
#define BRUNEL_STEP(kk, xk)                                                   \
        {                                                                     \
            const int t = t0 + kk;                                            \
            int cI = V##kk;                                                   \
            int cE = S##kk - V##kk;                                           \
            float cur = 0.1f * (float)cE - 0.5f * (float)cI;                  \
            v = v * 0.95f + (cur + xk);                                       \
            bool s = act && (v >= 1.0f);                                      \
            float sflag = s ? 1.0f : 0.0f;                                    \
            float vout  = s ? 0.0f : v;                                       \
            if (act && q == 0) {                                              \
                size_t o = ((size_t)t * NB + b) * NN + i;                     \
                out_spk[o] = sflag;                                           \
                out_vs[o]  = vout;                                            \
            }                                                                 \
            v = vout;                                                         \
            unsigned long long bm = __ballot(s);                              \
            uint32_t wbits = compress_even(bm);                               \
            if (lane == 0) {                                                  \
                __hip_atomic_store(                                           \
                    &ring[((size_t)(t & (RING_SLOTS - 1)) * NB + b) * RW      \
                          + sl * 8 + wv],                                     \
                    wbits, __ATOMIC_RELAXED, __HIP_MEMORY_SCOPE_AGENT);       \
            }                                                                 \
        }
        BRUNEL_STEP(0, x0)
        BRUNEL_STEP(1, x1)
        BRUNEL_STEP(2, x2)
        BRUNEL_STEP(3, x3)
#undef BRUNEL_STEP

        // ---- arrive: per-wave store drain, block barrier, relaxed add ----
        asm volatile("s_waitcnt vmcnt(0)" ::: "memory");  // ring stores at LLC
        __syncthreads();                                  // all 8 waves drained
        if (tx == 0)
            __hip_atomic_fetch_add(barc + (size_t)m * BARSTRIDE, 1,
                                   __ATOMIC_RELAXED, __HIP_MEMORY_SCOPE_AGENT);
    }
}

// ---------------------------------------------------------------------------
extern "C" void kernel_launch(void* const* d_in, const int* in_sizes, int n_in,
                              void* d_out, int out_size, void* d_ws, size_t ws_size,
                              hipStream_t stream)
{
    const float* ext = (const float*)d_in[0];   // [T,B,N] fp32
    const float* W   = (const float*)d_in[1];   // [N,N]   fp32

    float* out_spk = (float*)d_out;                          // [T,B,N]
    float* out_vs  = out_spk + (size_t)TSTEPS * NB * NN;     // [T,B,N]

    uint8_t*  ws   = (uint8_t*)d_ws;
    uint32_t* mask = (uint32_t*)(ws);
    int*      barc = (int*)(ws + BAR_OFF);
    uint32_t* ring = (uint32_t*)(ws + RING_OFF);

    // zero mask (pad columns must read 0) + per-chunk counters + ring
    hipMemsetAsync(ws, 0, ZERO_BYTES, stream);

    dim3 gmask(NIPAD / 256, NN);   // (20, 5000), 256 threads
    _Brunel_build_mask<<<gmask, 256, 0, stream>>>(W, mask);

    _Brunel_persist<<<NBLK, IPB, 0, stream>>>(ext, mask, ring, barc,
                                              out_spk, out_vs);
}